// Round 2
// baseline (1064.015 us; speedup 1.0000x reference)
//
#include <hip/hip_runtime.h>

#define Hh 240
#define Ww 304
#define IN_CH 16
#define OUT_CH 32
#define Kk 3
#define Bb 8
#define N_PER 65536
#define N_EV (Bb * N_PER)      // 524288
#define CIN (IN_CH + 2)        // 18
#define NSEG (Bb * Hh * Ww)    // 583680
#define WSZ (Kk * Kk * CIN * OUT_CH)  // 5184

// ---------------- scatter: per-event atomic accumulate into dense grid ------
__global__ __launch_bounds__(256) void scatter_kernel(
    const float* __restrict__ events, const float* __restrict__ features,
    const int* __restrict__ offsets, float* __restrict__ sums,
    float* __restrict__ cnt, int* __restrict__ keys) {
  int i = blockIdx.x * blockDim.x + threadIdx.x;
  if (i >= N_EV) return;
  float4 ev = ((const float4*)events)[i];  // x, y, t, pol
  int yi = (int)rintf(ev.y * (float)Hh);
  yi = min(max(yi, 0), Hh - 1);
  int xi = (int)rintf(ev.x * (float)Ww);
  xi = min(max(xi, 0), Ww - 1);
  int b = 0;
#pragma unroll
  for (int j = 0; j < Bb; j++) b += (offsets[j] <= i) ? 1 : 0;
  int key = (b * Hh + yi) * Ww + xi;
  keys[i] = key;
  float* s = sums + (size_t)key * CIN;
  atomicAdd(s + 0, ev.w);
  atomicAdd(s + 1, 1.0f - ev.w);
#pragma unroll
  for (int c = 0; c < IN_CH; c++)
    atomicAdd(s + 2 + c, features[(size_t)i * IN_CH + c]);
  atomicAdd(cnt + key, 1.0f);
}

// ---------------- normalize: dense = sum / max(cnt,1) -----------------------
__global__ __launch_bounds__(256) void normalize_kernel(
    float* __restrict__ dense, const float* __restrict__ cnt) {
  int i = blockIdx.x * blockDim.x + threadIdx.x;
  if (i >= NSEG * CIN) return;
  float c = cnt[i / CIN];
  dense[i] = dense[i] / fmaxf(c, 1.0f);
}

// ---------------- fused conv(3x3,18->32) at event pixel + bias --------------
// 32 threads per event: lane o computes out channel o. Weights+bias in LDS.
__global__ __launch_bounds__(256) void conv_gather_kernel(
    const float* __restrict__ dense, const float* __restrict__ weight,
    const float* __restrict__ bias, const int* __restrict__ keys,
    float* __restrict__ out) {
  __shared__ float w[WSZ];
  __shared__ float bs[OUT_CH];
  for (int t = threadIdx.x; t < WSZ; t += blockDim.x) w[t] = weight[t];
  if (threadIdx.x < OUT_CH) bs[threadIdx.x] = bias[threadIdx.x];
  __syncthreads();
  int gid = blockIdx.x * blockDim.x + threadIdx.x;
  int ev = gid >> 5;
  int o = gid & 31;
  if (ev >= N_EV) return;
  int key = keys[ev];
  int xi = key % Ww;
  int rem = key / Ww;
  int yi = rem % Hh;
  int b = rem / Hh;
  float acc = bs[o];
  for (int ky = 0; ky < Kk; ky++) {
    int yy = yi + ky - 1;
    if (yy < 0 || yy >= Hh) continue;
    for (int kx = 0; kx < Kk; kx++) {
      int xx = xi + kx - 1;
      if (xx < 0 || xx >= Ww) continue;
      const float* dp = dense + (size_t)((b * Hh + yy) * Ww + xx) * CIN;
      const float* wp = w + (ky * Kk + kx) * CIN * OUT_CH;
#pragma unroll
      for (int ci = 0; ci < CIN; ci++) acc += dp[ci] * wp[ci * OUT_CH + o];
    }
  }
  out[(size_t)ev * OUT_CH + o] = acc;
}

extern "C" void kernel_launch(void* const* d_in, const int* in_sizes, int n_in,
                              void* d_out, int out_size, void* d_ws,
                              size_t ws_size, hipStream_t stream) {
  const float* events = (const float*)d_in[0];
  const float* features = (const float*)d_in[1];
  const float* weight = (const float*)d_in[2];
  const float* bias = (const float*)d_in[3];
  const int* offsets = (const int*)d_in[4];
  float* out = (float*)d_out;

  float* dense = (float*)d_ws;                    // NSEG*CIN floats
  float* cnt = dense + (size_t)NSEG * CIN;        // NSEG floats
  int* keys = (int*)(cnt + NSEG);                 // N_EV ints

  // zero the accumulators (dense + cnt are contiguous)
  hipMemsetAsync(d_ws, 0, (size_t)(NSEG * (CIN + 1)) * sizeof(float), stream);

  scatter_kernel<<<(N_EV + 255) / 256, 256, 0, stream>>>(
      events, features, offsets, dense, cnt, keys);
  normalize_kernel<<<(NSEG * CIN + 255) / 256, 256, 0, stream>>>(dense, cnt);
  conv_gather_kernel<<<(N_EV * 32) / 256, 256, 0, stream>>>(
      dense, weight, bias, keys, out);
}

// Round 3
// 337.819 us; speedup vs baseline: 3.1497x; 3.1497x over previous
//
#include <hip/hip_runtime.h>

#define Hh 240
#define Ww 304
#define IN_CH 16
#define OUT_CH 32
#define Bb 8
#define N_PER 65536
#define N_EV (Bb * N_PER)      // 524288
#define CIN (IN_CH + 2)        // 18
#define NSEG (Bb * Hh * Ww)    // 583680 = 570 * 1024
#define NBLK 570               // scan blocks of 1024 elems

__device__ __forceinline__ int event_key(float4 ev, const int* __restrict__ offsets, int i) {
  int yi = (int)rintf(ev.y * (float)Hh);
  yi = min(max(yi, 0), Hh - 1);
  int xi = (int)rintf(ev.x * (float)Ww);
  xi = min(max(xi, 0), Ww - 1);
  int b = 0;
#pragma unroll
  for (int j = 0; j < Bb; j++) b += (offsets[j] <= i) ? 1 : 0;
  return (b * Hh + yi) * Ww + xi;
}

// ---- A: histogram of events per pixel (int atomics) ------------------------
__global__ __launch_bounds__(256) void hist_kernel(
    const float* __restrict__ events, const int* __restrict__ offsets,
    int* __restrict__ hist) {
  int i = blockIdx.x * blockDim.x + threadIdx.x;
  float4 ev = ((const float4*)events)[i];
  atomicAdd(&hist[event_key(ev, offsets, i)], 1);
}

// ---- S1: per-1024-block exclusive scan + block totals ----------------------
__global__ __launch_bounds__(256) void scan1_kernel(
    const int* __restrict__ hist, int* __restrict__ baseLocal,
    int* __restrict__ blockSum) {
  __shared__ int lds[256];
  int b = blockIdx.x, t = threadIdx.x;
  int idx = b * 1024 + t * 4;
  int4 v = *(const int4*)(hist + idx);
  int s0 = v.x, s1 = s0 + v.y, s2 = s1 + v.z, s3 = s2 + v.w;
  lds[t] = s3;
  __syncthreads();
  int val = s3;
  for (int off = 1; off < 256; off <<= 1) {
    int n = (t >= off) ? lds[t - off] : 0;
    __syncthreads();
    val += n;
    lds[t] = val;
    __syncthreads();
  }
  int excl = val - s3;
  int4 o;
  o.x = excl; o.y = excl + s0; o.z = excl + s1; o.w = excl + s2;
  *(int4*)(baseLocal + idx) = o;
  if (t == 255) blockSum[b] = val;
}

// ---- S2: scan of 570 block totals -----------------------------------------
__global__ __launch_bounds__(1024) void scan2_kernel(
    const int* __restrict__ blockSum, int* __restrict__ blockOffset) {
  __shared__ int lds[1024];
  int t = threadIdx.x;
  int v = (t < NBLK) ? blockSum[t] : 0;
  lds[t] = v;
  __syncthreads();
  int val = v;
  for (int off = 1; off < 1024; off <<= 1) {
    int n = (t >= off) ? lds[t - off] : 0;
    __syncthreads();
    val += n;
    lds[t] = val;
    __syncthreads();
  }
  if (t < NBLK) blockOffset[t] = val - v;
  if (t == 0) blockOffset[NBLK] = lds[1023];  // = N_EV
}

// ---- C: place events into sorted order (atomicSub consumes hist) -----------
__global__ __launch_bounds__(256) void place_kernel(
    const float* __restrict__ events, const int* __restrict__ offsets,
    const int* __restrict__ baseLocal, const int* __restrict__ blockOffset,
    int* __restrict__ hist, int* __restrict__ order) {
  int i = blockIdx.x * blockDim.x + threadIdx.x;
  float4 ev = ((const float4*)events)[i];
  int key = event_key(ev, offsets, i);
  int old = atomicSub(&hist[key], 1);
  int pos = baseLocal[key] + blockOffset[key >> 10] + old - 1;
  int pol = (ev.w != 0.0f) ? 1 : 0;
  order[pos] = i | (pol << 31);
}

// ---- D1: per-pixel gather accumulate + normalize + compact active list -----
__global__ __launch_bounds__(256) void accum_kernel(
    const int* __restrict__ baseLocal, const int* __restrict__ blockOffset,
    const int* __restrict__ order, const float* __restrict__ features,
    float* __restrict__ dense, int* __restrict__ worklist,
    int* __restrict__ nActive) {
  int p = blockIdx.x * blockDim.x + threadIdx.x;  // grid covers NSEG exactly
  int bo = blockOffset[p >> 10];
  int base = baseLocal[p] + bo;
  int nxt = ((p & 1023) != 1023) ? (baseLocal[p + 1] + bo)
                                 : blockOffset[(p >> 10) + 1];
  int c = nxt - base;
  float acc[CIN];
#pragma unroll
  for (int k = 0; k < CIN; k++) acc[k] = 0.0f;
  for (int j = 0; j < c; j++) {
    int e = order[base + j];
    int i = e & 0x7fffffff;
    float pol = (float)((unsigned)e >> 31);
    acc[0] += pol;
    acc[1] += 1.0f - pol;
    const float4* f = (const float4*)(features + (size_t)i * IN_CH);
    float4 f0 = f[0], f1 = f[1], f2 = f[2], f3 = f[3];
    acc[2] += f0.x; acc[3] += f0.y; acc[4] += f0.z; acc[5] += f0.w;
    acc[6] += f1.x; acc[7] += f1.y; acc[8] += f1.z; acc[9] += f1.w;
    acc[10] += f2.x; acc[11] += f2.y; acc[12] += f2.z; acc[13] += f2.w;
    acc[14] += f3.x; acc[15] += f3.y; acc[16] += f3.z; acc[17] += f3.w;
  }
  float inv = 1.0f / fmaxf((float)c, 1.0f);
  float* dp = dense + (size_t)p * CIN;
#pragma unroll
  for (int k = 0; k < CIN; k += 2) {
    float2 w2 = make_float2(acc[k] * inv, acc[k + 1] * inv);
    *(float2*)(dp + k) = w2;
  }
  if (c > 0) {
    int w = atomicAdd(nActive, 1);
    worklist[w] = p;
  }
}

// ---- D2: conv 3x3x18->32 at each active pixel, scatter to its events -------
__global__ __launch_bounds__(256) void conv_kernel(
    const float* __restrict__ dense, const float* __restrict__ weight,
    const float* __restrict__ bias, const int* __restrict__ baseLocal,
    const int* __restrict__ blockOffset, const int* __restrict__ order,
    const int* __restrict__ worklist, const int* __restrict__ nActive,
    float* __restrict__ out) {
  int t = blockIdx.x * blockDim.x + threadIdx.x;
  if (t >= *nActive) return;
  int p = worklist[t];
  int xi = p % Ww;
  int rem = p / Ww;
  int yi = rem % Hh;
  int b = rem / Hh;
  float acc[OUT_CH];
#pragma unroll
  for (int o = 0; o < OUT_CH; o++) acc[o] = bias[o];  // uniform -> s_load
#pragma unroll 1
  for (int ky = 0; ky < 3; ky++) {
    int yy = yi + ky - 1;
    if (yy < 0 || yy >= Hh) continue;
#pragma unroll 1
    for (int kx = 0; kx < 3; kx++) {
      int xx = xi + kx - 1;
      if (xx < 0 || xx >= Ww) continue;
      const float* dp = dense + (size_t)((b * Hh + yy) * Ww + xx) * CIN;
      float d[CIN];
#pragma unroll
      for (int k = 0; k < CIN; k += 2) {
        float2 v = *(const float2*)(dp + k);
        d[k] = v.x; d[k + 1] = v.y;
      }
      const float* wp = weight + (ky * 3 + kx) * CIN * OUT_CH;
#pragma unroll
      for (int ci = 0; ci < CIN; ci++) {
#pragma unroll
        for (int o = 0; o < OUT_CH; o++)
          acc[o] += d[ci] * wp[ci * OUT_CH + o];  // uniform idx -> s_load
      }
    }
  }
  // scatter to this pixel's events
  int bo = blockOffset[p >> 10];
  int base = baseLocal[p] + bo;
  int nxt = ((p & 1023) != 1023) ? (baseLocal[p + 1] + bo)
                                 : blockOffset[(p >> 10) + 1];
  for (int j = 0; j < nxt - base; j++) {
    int ev = order[base + j] & 0x7fffffff;
    float* op = out + (size_t)ev * OUT_CH;
#pragma unroll
    for (int o = 0; o < OUT_CH; o += 4)
      *(float4*)(op + o) = make_float4(acc[o], acc[o + 1], acc[o + 2], acc[o + 3]);
  }
}

extern "C" void kernel_launch(void* const* d_in, const int* in_sizes, int n_in,
                              void* d_out, int out_size, void* d_ws,
                              size_t ws_size, hipStream_t stream) {
  const float* events = (const float*)d_in[0];
  const float* features = (const float*)d_in[1];
  const float* weight = (const float*)d_in[2];
  const float* bias = (const float*)d_in[3];
  const int* offsets = (const int*)d_in[4];
  float* out = (float*)d_out;

  float* dense = (float*)d_ws;                        // NSEG*CIN f32
  int* order = (int*)(dense + (size_t)NSEG * CIN);    // N_EV
  int* hist = order + N_EV;                           // NSEG
  int* baseLocal = hist + NSEG;                       // NSEG
  int* worklist = baseLocal + NSEG;                   // NSEG
  int* blockOffset = worklist + NSEG;                 // NBLK+1 (pad 1024)
  int* blockSum = blockOffset + 1024;                 // NBLK (pad 1024)
  int* nActive = blockSum + 1024;                     // 1

  hipMemsetAsync(hist, 0, (size_t)NSEG * sizeof(int), stream);
  hipMemsetAsync(nActive, 0, sizeof(int), stream);

  hist_kernel<<<N_EV / 256, 256, 0, stream>>>(events, offsets, hist);
  scan1_kernel<<<NBLK, 256, 0, stream>>>(hist, baseLocal, blockSum);
  scan2_kernel<<<1, 1024, 0, stream>>>(blockSum, blockOffset);
  place_kernel<<<N_EV / 256, 256, 0, stream>>>(events, offsets, baseLocal,
                                               blockOffset, hist, order);
  accum_kernel<<<NSEG / 256, 256, 0, stream>>>(baseLocal, blockOffset, order,
                                               features, dense, worklist,
                                               nActive);
  conv_kernel<<<NSEG / 256, 256, 0, stream>>>(dense, weight, bias, baseLocal,
                                              blockOffset, order, worklist,
                                              nActive, out);
}

// Round 4
// 332.158 us; speedup vs baseline: 3.2033x; 1.0170x over previous
//
#include <hip/hip_runtime.h>

#define Hh 240
#define Ww 304
#define IN_CH 16
#define OUT_CH 32
#define Bb 8
#define N_PER 65536
#define N_EV (Bb * N_PER)      // 524288
#define CIN (IN_CH + 2)        // 18
#define NSEG (Bb * Hh * Ww)    // 583680 = 570 * 1024
#define NBLK 570               // scan blocks of 1024 elems

__device__ __forceinline__ unsigned short f2bf(float x) {
  unsigned u = __float_as_uint(x);
  unsigned r = u + 0x7fffu + ((u >> 16) & 1u);  // RNE
  return (unsigned short)(r >> 16);
}
__device__ __forceinline__ float bf2f(unsigned short b) {
  return __uint_as_float(((unsigned)b) << 16);
}

// ---- A: histogram + rank per event (one atomic pass) -----------------------
__global__ __launch_bounds__(256) void hist_rank_kernel(
    const float* __restrict__ events, const int* __restrict__ offsets,
    int* __restrict__ hist, int* __restrict__ keyArr, int* __restrict__ rankArr) {
  int i = blockIdx.x * blockDim.x + threadIdx.x;
  float4 ev = ((const float4*)events)[i];
  int yi = (int)rintf(ev.y * (float)Hh);
  yi = min(max(yi, 0), Hh - 1);
  int xi = (int)rintf(ev.x * (float)Ww);
  xi = min(max(xi, 0), Ww - 1);
  int b = 0;
#pragma unroll
  for (int j = 0; j < Bb; j++) b += (offsets[j] <= i) ? 1 : 0;
  int key = (b * Hh + yi) * Ww + xi;
  int pol = (ev.w != 0.0f) ? 1 : 0;
  keyArr[i] = key | (pol << 31);
  rankArr[i] = atomicAdd(&hist[key], 1);
}

// ---- S1: per-1024-block exclusive scan + block totals ----------------------
__global__ __launch_bounds__(256) void scan1_kernel(
    const int* __restrict__ hist, int* __restrict__ baseLocal,
    int* __restrict__ blockSum) {
  __shared__ int lds[256];
  int b = blockIdx.x, t = threadIdx.x;
  int idx = b * 1024 + t * 4;
  int4 v = *(const int4*)(hist + idx);
  int s0 = v.x, s1 = s0 + v.y, s2 = s1 + v.z, s3 = s2 + v.w;
  lds[t] = s3;
  __syncthreads();
  int val = s3;
  for (int off = 1; off < 256; off <<= 1) {
    int n = (t >= off) ? lds[t - off] : 0;
    __syncthreads();
    val += n;
    lds[t] = val;
    __syncthreads();
  }
  int excl = val - s3;
  int4 o;
  o.x = excl; o.y = excl + s0; o.z = excl + s1; o.w = excl + s2;
  *(int4*)(baseLocal + idx) = o;
  if (t == 255) blockSum[b] = val;
}

// ---- S2: scan of 570 block totals -----------------------------------------
__global__ __launch_bounds__(1024) void scan2_kernel(
    const int* __restrict__ blockSum, int* __restrict__ blockOffset) {
  __shared__ int lds[1024];
  int t = threadIdx.x;
  int v = (t < NBLK) ? blockSum[t] : 0;
  lds[t] = v;
  __syncthreads();
  int val = v;
  for (int off = 1; off < 1024; off <<= 1) {
    int n = (t >= off) ? lds[t - off] : 0;
    __syncthreads();
    val += n;
    lds[t] = val;
    __syncthreads();
  }
  if (t < NBLK) blockOffset[t] = val - v;
  if (t == 0) blockOffset[NBLK] = lds[1023];  // = N_EV
}

// ---- B: scatter features (bf16) + meta into sorted order -------------------
// Coalesced reads of features; one random 32B+4B write per event.
__global__ __launch_bounds__(256) void scatter_feat_kernel(
    const float* __restrict__ features, const int* __restrict__ keyArr,
    const int* __restrict__ rankArr, const int* __restrict__ baseLocal,
    const int* __restrict__ blockOffset, uint4* __restrict__ sortedFeat,
    int* __restrict__ sortedMeta) {
  int i = blockIdx.x * blockDim.x + threadIdx.x;
  int meta = keyArr[i];
  int key = meta & 0x7fffffff;
  int pos = baseLocal[key] + blockOffset[key >> 10] + rankArr[i];
  const float4* f = (const float4*)(features + (size_t)i * IN_CH);
  float4 f0 = f[0], f1 = f[1], f2 = f[2], f3 = f[3];
  uint4 w0, w1;
  w0.x = (unsigned)f2bf(f0.x) | ((unsigned)f2bf(f0.y) << 16);
  w0.y = (unsigned)f2bf(f0.z) | ((unsigned)f2bf(f0.w) << 16);
  w0.z = (unsigned)f2bf(f1.x) | ((unsigned)f2bf(f1.y) << 16);
  w0.w = (unsigned)f2bf(f1.z) | ((unsigned)f2bf(f1.w) << 16);
  w1.x = (unsigned)f2bf(f2.x) | ((unsigned)f2bf(f2.y) << 16);
  w1.y = (unsigned)f2bf(f2.z) | ((unsigned)f2bf(f2.w) << 16);
  w1.z = (unsigned)f2bf(f3.x) | ((unsigned)f2bf(f3.y) << 16);
  w1.w = (unsigned)f2bf(f3.z) | ((unsigned)f2bf(f3.w) << 16);
  sortedFeat[(size_t)pos * 2] = w0;
  sortedFeat[(size_t)pos * 2 + 1] = w1;
  sortedMeta[pos] = i | (meta & 0x80000000);
}

// ---- C: per-pixel streaming accumulate + normalize + compact ---------------
__global__ __launch_bounds__(256) void accum_kernel(
    const int* __restrict__ baseLocal, const int* __restrict__ blockOffset,
    const int* __restrict__ sortedMeta, const uint4* __restrict__ sortedFeat,
    float* __restrict__ dense, int* __restrict__ worklist,
    int* __restrict__ nActive) {
  int p = blockIdx.x * blockDim.x + threadIdx.x;  // grid covers NSEG exactly
  int bo = blockOffset[p >> 10];
  int base = baseLocal[p] + bo;
  int nxt = ((p & 1023) != 1023) ? (baseLocal[p + 1] + bo)
                                 : blockOffset[(p >> 10) + 1];
  int c = nxt - base;
  float acc[CIN];
#pragma unroll
  for (int k = 0; k < CIN; k++) acc[k] = 0.0f;
  for (int j = 0; j < c; j++) {
    int e = sortedMeta[base + j];
    float pol = (float)((unsigned)e >> 31);
    acc[0] += pol;
    acc[1] += 1.0f - pol;
    uint4 w0 = sortedFeat[(size_t)(base + j) * 2];
    uint4 w1 = sortedFeat[(size_t)(base + j) * 2 + 1];
    acc[2] += bf2f((unsigned short)w0.x);  acc[3] += bf2f((unsigned short)(w0.x >> 16));
    acc[4] += bf2f((unsigned short)w0.y);  acc[5] += bf2f((unsigned short)(w0.y >> 16));
    acc[6] += bf2f((unsigned short)w0.z);  acc[7] += bf2f((unsigned short)(w0.z >> 16));
    acc[8] += bf2f((unsigned short)w0.w);  acc[9] += bf2f((unsigned short)(w0.w >> 16));
    acc[10] += bf2f((unsigned short)w1.x); acc[11] += bf2f((unsigned short)(w1.x >> 16));
    acc[12] += bf2f((unsigned short)w1.y); acc[13] += bf2f((unsigned short)(w1.y >> 16));
    acc[14] += bf2f((unsigned short)w1.z); acc[15] += bf2f((unsigned short)(w1.z >> 16));
    acc[16] += bf2f((unsigned short)w1.w); acc[17] += bf2f((unsigned short)(w1.w >> 16));
  }
  float inv = 1.0f / fmaxf((float)c, 1.0f);
  float* dp = dense + (size_t)p * CIN;
#pragma unroll
  for (int k = 0; k < CIN; k += 2)
    *(float2*)(dp + k) = make_float2(acc[k] * inv, acc[k + 1] * inv);
  if (c > 0) {
    int w = atomicAdd(nActive, 1);
    worklist[w] = p;
  }
}

// ---- D: conv 3x3x18->32 at each active pixel, scatter to its events --------
__global__ __launch_bounds__(256) void conv_kernel(
    const float* __restrict__ dense, const float* __restrict__ weight,
    const float* __restrict__ bias, const int* __restrict__ baseLocal,
    const int* __restrict__ blockOffset, const int* __restrict__ sortedMeta,
    const int* __restrict__ worklist, const int* __restrict__ nActive,
    float* __restrict__ out) {
  int t = blockIdx.x * blockDim.x + threadIdx.x;
  if (t >= *nActive) return;
  int p = worklist[t];
  int xi = p % Ww;
  int rem = p / Ww;
  int yi = rem % Hh;
  int b = rem / Hh;
  float acc[OUT_CH];
#pragma unroll
  for (int o = 0; o < OUT_CH; o++) acc[o] = bias[o];  // uniform -> s_load
#pragma unroll 1
  for (int ky = 0; ky < 3; ky++) {
    int yy = yi + ky - 1;
    if (yy < 0 || yy >= Hh) continue;
#pragma unroll 1
    for (int kx = 0; kx < 3; kx++) {
      int xx = xi + kx - 1;
      if (xx < 0 || xx >= Ww) continue;
      const float* dp = dense + (size_t)((b * Hh + yy) * Ww + xx) * CIN;
      float d[CIN];
      float4 v0 = *(const float4*)(dp);
      float4 v1 = *(const float4*)(dp + 4);
      float4 v2 = *(const float4*)(dp + 8);
      float4 v3 = *(const float4*)(dp + 12);
      float2 v4 = *(const float2*)(dp + 16);
      d[0] = v0.x; d[1] = v0.y; d[2] = v0.z; d[3] = v0.w;
      d[4] = v1.x; d[5] = v1.y; d[6] = v1.z; d[7] = v1.w;
      d[8] = v2.x; d[9] = v2.y; d[10] = v2.z; d[11] = v2.w;
      d[12] = v3.x; d[13] = v3.y; d[14] = v3.z; d[15] = v3.w;
      d[16] = v4.x; d[17] = v4.y;
      const float* wp = weight + (ky * 3 + kx) * CIN * OUT_CH;
#pragma unroll
      for (int ci = 0; ci < CIN; ci++) {
#pragma unroll
        for (int o = 0; o < OUT_CH; o++)
          acc[o] += d[ci] * wp[ci * OUT_CH + o];  // uniform idx -> s_load
      }
    }
  }
  int bo = blockOffset[p >> 10];
  int base = baseLocal[p] + bo;
  int nxt = ((p & 1023) != 1023) ? (baseLocal[p + 1] + bo)
                                 : blockOffset[(p >> 10) + 1];
  for (int j = 0; j < nxt - base; j++) {
    int ev = sortedMeta[base + j] & 0x7fffffff;
    float* op = out + (size_t)ev * OUT_CH;
#pragma unroll
    for (int o = 0; o < OUT_CH; o += 4)
      *(float4*)(op + o) = make_float4(acc[o], acc[o + 1], acc[o + 2], acc[o + 3]);
  }
}

extern "C" void kernel_launch(void* const* d_in, const int* in_sizes, int n_in,
                              void* d_out, int out_size, void* d_ws,
                              size_t ws_size, hipStream_t stream) {
  const float* events = (const float*)d_in[0];
  const float* features = (const float*)d_in[1];
  const float* weight = (const float*)d_in[2];
  const float* bias = (const float*)d_in[3];
  const int* offsets = (const int*)d_in[4];
  float* out = (float*)d_out;

  float* dense = (float*)d_ws;                        // NSEG*CIN f32
  uint4* sortedFeat = (uint4*)(dense + (size_t)NSEG * CIN);  // N_EV*32B
  int* sortedMeta = (int*)(sortedFeat + (size_t)N_EV * 2);   // N_EV
  int* keyArr = sortedMeta + N_EV;                    // N_EV
  int* rankArr = keyArr + N_EV;                       // N_EV
  int* hist = rankArr + N_EV;                         // NSEG
  int* baseLocal = hist + NSEG;                       // NSEG
  int* worklist = baseLocal + NSEG;                   // NSEG
  int* blockOffset = worklist + NSEG;                 // NBLK+1 (pad 1024)
  int* blockSum = blockOffset + 1024;                 // NBLK (pad 1024)
  int* nActive = blockSum + 1024;                     // 1

  hipMemsetAsync(hist, 0, (size_t)NSEG * sizeof(int), stream);
  hipMemsetAsync(nActive, 0, sizeof(int), stream);

  hist_rank_kernel<<<N_EV / 256, 256, 0, stream>>>(events, offsets, hist,
                                                   keyArr, rankArr);
  scan1_kernel<<<NBLK, 256, 0, stream>>>(hist, baseLocal, blockSum);
  scan2_kernel<<<1, 1024, 0, stream>>>(blockSum, blockOffset);
  scatter_feat_kernel<<<N_EV / 256, 256, 0, stream>>>(
      features, keyArr, rankArr, baseLocal, blockOffset, sortedFeat, sortedMeta);
  accum_kernel<<<NSEG / 256, 256, 0, stream>>>(baseLocal, blockOffset,
                                               sortedMeta, sortedFeat, dense,
                                               worklist, nActive);
  conv_kernel<<<NSEG / 256, 256, 0, stream>>>(dense, weight, bias, baseLocal,
                                              blockOffset, sortedMeta,
                                              worklist, nActive, out);
}